// Round 4
// baseline (5833.982 us; speedup 1.0000x reference)
//
#include <hip/hip_runtime.h>
#include <hip/hip_bf16.h>

#define B_ 32
#define S_ 64
#define H_ 512
#define V_ 32000
#define T_ 64
#define NB_ 256   // persistent grid size

typedef __bf16 bf16x8 __attribute__((ext_vector_type(8)));
typedef float f32x4 __attribute__((ext_vector_type(4)));

__device__ __forceinline__ float fast_tanh(float x) {
  float e = __expf(2.0f * x);
  return 1.0f - 2.0f / (e + 1.0f);
}
__device__ __forceinline__ float fast_sigmoid(float x) {
  return 1.0f / (1.0f + __expf(-x));
}

// ---------------- prep kernels ----------------

__global__ __launch_bounds__(256) void k_emb_gather(const int* __restrict__ target,
    const float* __restrict__ emb, float* __restrict__ emb_all) {
  int row = blockIdx.x;                 // t*32 + b
  int t = row >> 5, b = row & 31;
  int tok = (t == 0) ? 0 : target[b * T_ + t - 1];
  const float* src = emb + (size_t)tok * H_;
  float* dst = emb_all + (size_t)row * H_;
  for (int j = threadIdx.x; j < H_; j += 256) dst[j] = src[j];
}

__global__ __launch_bounds__(256) void k_init(const float* __restrict__ ehs,
    float* __restrict__ h_glob, int* __restrict__ flags) {
  int i = blockIdx.x * 256 + threadIdx.x;
  if (i < B_ * H_) h_glob[i] = ehs[i];
  if (i < NB_) flags[i] = 0;
}

// ---------------- generic fp32 GEMM: C[M,N] = A[M,K] @ B[N,K]^T + bias ----------------

__global__ __launch_bounds__(256) void k_gemm_f32(
    const float* __restrict__ A, int lda,
    const float* __restrict__ B, int ldb,
    const float* __restrict__ bias,
    float* __restrict__ C, int ldc, int K) {
  __shared__ float As[16][64];
  __shared__ float Bs[16][64];
  const int tid = threadIdx.x;
  const int tx = tid & 15, ty = tid >> 4;
  const int m0 = blockIdx.y * 64, n0 = blockIdx.x * 64;
  const int r = tid >> 2, c4 = (tid & 3) * 4;
  float acc[4][4] = {};
  for (int k0 = 0; k0 < K; k0 += 16) {
    const float4 av = *(const float4*)(A + (size_t)(m0 + r) * lda + k0 + c4);
    const float4 bv = *(const float4*)(B + (size_t)(n0 + r) * ldb + k0 + c4);
    __syncthreads();
    As[c4 + 0][r] = av.x; As[c4 + 1][r] = av.y; As[c4 + 2][r] = av.z; As[c4 + 3][r] = av.w;
    Bs[c4 + 0][r] = bv.x; Bs[c4 + 1][r] = bv.y; Bs[c4 + 2][r] = bv.z; Bs[c4 + 3][r] = bv.w;
    __syncthreads();
#pragma unroll
    for (int k = 0; k < 16; ++k) {
      const float4 a = *(const float4*)(&As[k][ty * 4]);
      const float4 b = *(const float4*)(&Bs[k][tx * 4]);
      const float a4[4] = {a.x, a.y, a.z, a.w};
      const float b4[4] = {b.x, b.y, b.z, b.w};
#pragma unroll
      for (int i = 0; i < 4; ++i)
#pragma unroll
        for (int j = 0; j < 4; ++j)
          acc[i][j] = fmaf(a4[i], b4[j], acc[i][j]);
    }
  }
  const float4 bb = *(const float4*)(bias + n0 + tx * 4);
#pragma unroll
  for (int i = 0; i < 4; ++i) {
    float4 o;
    o.x = acc[i][0] + bb.x; o.y = acc[i][1] + bb.y;
    o.z = acc[i][2] + bb.z; o.w = acc[i][3] + bb.w;
    *(float4*)(C + (size_t)(m0 + ty * 4 + i) * ldc + n0 + tx * 4) = o;
  }
}

// ---------------- DIY grid barrier (normal launch, all 256 blocks resident) ----------------
// Arrive: after __syncthreads (drains this block's stores to L2), tid 0 does an
// agent-scope RELEASE store of `target` to flags[bid]; the release emits the
// L2 writeback so other XCDs can observe our data. Wait: thread tid polls
// flags[tid] (relaxed agent loads bypass stale caches), then one acquire
// threadfence invalidates stale lines, then __syncthreads.

__device__ __forceinline__ void grid_bar(int* flags, int target) {
  __syncthreads();
  if (threadIdx.x == 0)
    __hip_atomic_store(&flags[blockIdx.x], target, __ATOMIC_RELEASE,
                       __HIP_MEMORY_SCOPE_AGENT);
  while (__hip_atomic_load(&flags[threadIdx.x], __ATOMIC_RELAXED,
                           __HIP_MEMORY_SCOPE_AGENT) < target)
    __builtin_amdgcn_s_sleep(2);
  __threadfence();
  __syncthreads();
}

// ---------------- persistent recurrence (normal launch, 256 blocks) ----------------
// Phase A: qgh[b][row] = h[b] . [Wq; W_hh][row] (+bq), weights register-stationary.
// Phase B: per-(js,b) attention + GRU gates.

__global__ __launch_bounds__(256) void k_recur(
    const float* __restrict__ Wq, const float* __restrict__ W_hh,
    const float* __restrict__ bq,
    const float* __restrict__ kproj, const float* __restrict__ enc,
    const float* __restrict__ Wv, const float* __restrict__ bv,
    const float* __restrict__ W_ih, const float* __restrict__ giemb,
    const float* __restrict__ b_hh,
    float* h_glob, float* qgh, int* flags,
    float* __restrict__ attn_out, __hip_bfloat16* __restrict__ Hall,
    float* __restrict__ hfin) {
  const int tid = threadIdx.x;
  const int bid = blockIdx.x;

  // phase A persistent weights: row = bid*8 + r, 16-float k-slice per thread
  const int r = tid >> 5, kc = tid & 31;
  const int arow = bid * 8 + r;
  const float* wrow = (arow < 512) ? (Wq + (size_t)arow * 512)
                                   : (W_hh + (size_t)(arow - 512) * 512);
  float4 w4[4];
#pragma unroll
  for (int i = 0; i < 4; ++i) w4[i] = *(const float4*)(wrow + kc * 16 + i * 4);
  const float abias = (arow < 512) ? bq[arow] : 0.f;

  // phase B ids, XCD-aware spread (bid%8 = XCD under round-robin)
  const int gx = bid & 7, u = bid >> 3;
  const int js = (u & 3) | ((gx & 1) << 2);   // 0..7
  const int b  = (u >> 2) | ((gx >> 1) << 3); // 0..31

  __shared__ float aq_s[256];
  __shared__ float q_s[512];
  __shared__ float red[256];
  __shared__ float w_s[64];
  __shared__ float ctx_s[512];
  __shared__ float gic_s[192];

  for (int t = 0; t < T_; ++t) {
    // ---- phase A ----
    for (int bb = 0; bb < B_; ++bb) {
      const float* hb = h_glob + bb * 512 + kc * 16;
      float p = 0.f;
#pragma unroll
      for (int i = 0; i < 4; ++i) {
        const float4 h4 = *(const float4*)(hb + i * 4);
        p += w4[i].x * h4.x + w4[i].y * h4.y + w4[i].z * h4.z + w4[i].w * h4.w;
      }
#pragma unroll
      for (int d = 16; d > 0; d >>= 1) p += __shfl_xor(p, d, 32);
      if (kc == 0) aq_s[r * 32 + bb] = p + abias;
    }
    __syncthreads();
    if (tid < 64) {
      const int bb = tid >> 1, hf = tid & 1;
      float4 v;
      v.x = aq_s[(hf * 4 + 0) * 32 + bb];
      v.y = aq_s[(hf * 4 + 1) * 32 + bb];
      v.z = aq_s[(hf * 4 + 2) * 32 + bb];
      v.w = aq_s[(hf * 4 + 3) * 32 + bb];
      *(float4*)(qgh + bb * 2048 + bid * 8 + hf * 4) = v;
    }
    grid_bar(flags, 2 * t + 1);

    // ---- phase B ----
    q_s[tid]       = qgh[b * 2048 + tid];
    q_s[tid + 256] = qgh[b * 2048 + 256 + tid];
    __syncthreads();
    {
      const int s = tid >> 2, part = tid & 3;
      const float* kp = kproj + ((size_t)(b * S_ + s)) * H_ + part * 128;
      const float* qp = q_s + part * 128;
      const float* wp = Wv + part * 128;
      float sc = 0.f;
      for (int k = 0; k < 128; k += 4) {
        const float4 kv = *(const float4*)(kp + k);
        const float4 qv = *(const float4*)(qp + k);
        const float4 wv = *(const float4*)(wp + k);
        sc = fmaf(wv.x, fast_tanh(qv.x + kv.x), sc);
        sc = fmaf(wv.y, fast_tanh(qv.y + kv.y), sc);
        sc = fmaf(wv.z, fast_tanh(qv.z + kv.z), sc);
        sc = fmaf(wv.w, fast_tanh(qv.w + kv.w), sc);
      }
      red[tid] = sc;
    }
    __syncthreads();
    if (tid < 64) {
      float sc = red[tid * 4] + red[tid * 4 + 1] + red[tid * 4 + 2] + red[tid * 4 + 3] + bv[0];
      float m = sc;
#pragma unroll
      for (int d = 32; d > 0; d >>= 1) m = fmaxf(m, __shfl_xor(m, d, 64));
      const float e = __expf(sc - m);
      float sum = e;
#pragma unroll
      for (int d = 32; d > 0; d >>= 1) sum += __shfl_xor(sum, d, 64);
      const float w = e / sum;
      w_s[tid] = w;
      if (js == 0) attn_out[((size_t)b * T_ + t) * S_ + tid] = w;
    }
    __syncthreads();
#pragma unroll
    for (int jj = 0; jj < 2; ++jj) {
      const int j = tid + jj * 256;
      float a = 0.f;
      const float* ep = enc + (size_t)(b * S_) * H_ + j;
      for (int s = 0; s < S_; ++s) a = fmaf(w_s[s], ep[s * 512], a);
      ctx_s[j] = a;
    }
    __syncthreads();
    if (tid < 192) {
      const int gg = tid >> 6, hp = tid & 63;
      const float* wr = W_ih + (size_t)(gg * 512 + js * 64 + hp) * 1024 + 512;
      float a = 0.f;
      for (int k = 0; k < 512; k += 4) {
        const float4 wv = *(const float4*)(wr + k);
        const float4 cv = *(const float4*)(ctx_s + k);
        a += wv.x * cv.x + wv.y * cv.y + wv.z * cv.z + wv.w * cv.w;
      }
      gic_s[tid] = a;
    }
    __syncthreads();
    if (tid < 64) {
      const int hh = js * 64 + tid;
      const size_t grow = ((size_t)t * B_ + b) * 1536;
      const int gbase = b * 2048 + 512;
      const float gir = giemb[grow + hh]        + gic_s[tid];
      const float giz = giemb[grow + 512 + hh]  + gic_s[64 + tid];
      const float gin = giemb[grow + 1024 + hh] + gic_s[128 + tid];
      const float ghr = qgh[gbase + hh]         + b_hh[hh];
      const float ghz = qgh[gbase + 512 + hh]   + b_hh[512 + hh];
      const float ghn = qgh[gbase + 1024 + hh]  + b_hh[1024 + hh];
      const float rg = fast_sigmoid(gir + ghr);
      const float zg = fast_sigmoid(giz + ghz);
      const float ng = fast_tanh(gin + rg * ghn);
      const float ho = h_glob[b * 512 + hh];
      const float hv = (1.f - zg) * ng + zg * ho;
      h_glob[b * 512 + hh] = hv;
      Hall[((size_t)b * T_ + t) * H_ + hh] = __float2bfloat16(hv);
      if (t == T_ - 1) hfin[b * 512 + hh] = hv;
    }
    grid_bar(flags, 2 * t + 2);
  }
}

// ---------------- logits GEMM: out[m,:] = Hall[m,:] @ Wo^T + bo (bf16 MFMA) ----------------
// m = b*64+t. grid (16 m-tiles, 250 n-tiles). LDS-staged coalesced epilogue.

__global__ __launch_bounds__(256) void k_logits(
    const __hip_bfloat16* __restrict__ Hall, const float* __restrict__ Wo,
    const float* __restrict__ bo, float* __restrict__ out0) {
  __shared__ float pool[128 * 68];      // 34.8 KB; Asub/Bsub alias the front
  __hip_bfloat16* Asub = (__hip_bfloat16*)pool;           // 4096 bf16
  __hip_bfloat16* Bsub = (__hip_bfloat16*)(pool + 2048);  // 4096 bf16
  const int tid = threadIdx.x;
  const int lane = tid & 63, wave = tid >> 6;
  const int wr = wave >> 1, wc = wave & 1;
  const int m0 = blockIdx.x * 128, n0 = blockIdx.y * 128;
  f32x4 acc[4][4];
#pragma unroll
  for (int i = 0; i < 4; ++i)
#pragma unroll
    for (int j = 0; j < 4; ++j) acc[i][j] = (f32x4){0.f, 0.f, 0.f, 0.f};

  for (int k0 = 0; k0 < 512; k0 += 32) {
    uint4 a_v[2];
#pragma unroll
    for (int rr = 0; rr < 2; ++rr) {
      const int seg = tid + rr * 256;
      const int row = seg >> 2, ks8 = (seg & 3) * 8;
      a_v[rr] = *(const uint4*)(Hall + (size_t)(m0 + row) * 512 + k0 + ks8);
    }
    float4 b_v[4];
#pragma unroll
    for (int rr = 0; rr < 4; ++rr) {
      const int idx = tid + rr * 256;
      const int n = idx >> 3, kg = (idx & 7) * 4;
      b_v[rr] = *(const float4*)(Wo + (size_t)(n0 + n) * 512 + k0 + kg);
    }
    __syncthreads();
#pragma unroll
    for (int rr = 0; rr < 2; ++rr) {
      const int seg = tid + rr * 256;
      *(uint4*)(Asub + seg * 8) = a_v[rr];
    }
#pragma unroll
    for (int rr = 0; rr < 4; ++rr) {
      const int idx = tid + rr * 256;
      const int n = idx >> 3, kg = (idx & 7) * 4;
      union { __hip_bfloat16 h[4]; uint2 u; } cv;
      cv.h[0] = __float2bfloat16(b_v[rr].x);
      cv.h[1] = __float2bfloat16(b_v[rr].y);
      cv.h[2] = __float2bfloat16(b_v[rr].z);
      cv.h[3] = __float2bfloat16(b_v[rr].w);
      *(uint2*)(Bsub + n * 32 + kg) = cv.u;
    }
    __syncthreads();
    bf16x8 af[4], bfr[4];
#pragma unroll
    for (int mi = 0; mi < 4; ++mi)
      af[mi] = *(const bf16x8*)(Asub + (wr * 64 + mi * 16 + (lane & 15)) * 32 + (lane >> 4) * 8);
#pragma unroll
    for (int ni = 0; ni < 4; ++ni)
      bfr[ni] = *(const bf16x8*)(Bsub + (wc * 64 + ni * 16 + (lane & 15)) * 32 + (lane >> 4) * 8);
#pragma unroll
    for (int mi = 0; mi < 4; ++mi)
#pragma unroll
      for (int ni = 0; ni < 4; ++ni)
        acc[mi][ni] = __builtin_amdgcn_mfma_f32_16x16x32_bf16(af[mi], bfr[ni], acc[mi][ni], 0, 0, 0);
  }

  // epilogue: stage each 128x64 half in LDS, then 256B-contiguous float4 stores
  float* Cs = pool;
  const int r4 = (lane >> 4) * 4, cc = lane & 15;
#pragma unroll
  for (int hf = 0; hf < 2; ++hf) {
    __syncthreads();
    if (wc == hf) {
#pragma unroll
      for (int ni = 0; ni < 4; ++ni) {
        const float bias = bo[n0 + hf * 64 + ni * 16 + cc];
#pragma unroll
        for (int mi = 0; mi < 4; ++mi)
#pragma unroll
          for (int i = 0; i < 4; ++i)
            Cs[(wr * 64 + mi * 16 + r4 + i) * 68 + ni * 16 + cc] = acc[mi][ni][i] + bias;
      }
    }
    __syncthreads();
    const int rowp = tid >> 4, colg = tid & 15;
#pragma unroll
    for (int pass = 0; pass < 8; ++pass) {
      const int row = pass * 16 + rowp;
      const float4 v = *(const float4*)(Cs + row * 68 + colg * 4);
      *(float4*)(out0 + (size_t)(m0 + row) * V_ + n0 + hf * 64 + colg * 4) = v;
    }
  }
}

// ---------------- in-place log_softmax over V, one row per block ----------------

__global__ __launch_bounds__(256) void k_lsm(float* __restrict__ out0) {
  __shared__ float rm[256];
  __shared__ float rs[256];
  const int row = blockIdx.x, tid = threadIdx.x;
  float4* p = (float4*)(out0 + (size_t)row * V_);
  float m = -INFINITY, s = 0.f;
  for (int i = tid; i < V_ / 4; i += 256) {
    const float4 v = p[i];
    const float mx = fmaxf(fmaxf(v.x, v.y), fmaxf(v.z, v.w));
    if (mx > m) { s *= __expf(m - mx); m = mx; }
    s += __expf(v.x - m) + __expf(v.y - m) + __expf(v.z - m) + __expf(v.w - m);
  }
  rm[tid] = m; rs[tid] = s;
  __syncthreads();
  for (int off = 128; off > 0; off >>= 1) {
    if (tid < off) {
      const float m2 = rm[tid + off], s2 = rs[tid + off];
      const float M = fmaxf(rm[tid], m2);
      rs[tid] = rs[tid] * __expf(rm[tid] - M) + s2 * __expf(m2 - M);
      rm[tid] = M;
    }
    __syncthreads();
  }
  const float lse = rm[0] + __logf(rs[0]);
  for (int i = tid; i < V_ / 4; i += 256) {
    float4 v = p[i];
    v.x -= lse; v.y -= lse; v.z -= lse; v.w -= lse;
    p[i] = v;
  }
}

// ---------------- host ----------------

extern "C" void kernel_launch(void* const* d_in, const int* in_sizes, int n_in,
                              void* d_out, int out_size, void* d_ws, size_t ws_size,
                              hipStream_t stream) {
  (void)in_sizes; (void)n_in; (void)out_size; (void)ws_size;
  const float* enc  = (const float*)d_in[0];
  const float* ehs  = (const float*)d_in[1];
  const int*   tgt  = (const int*)d_in[2];
  const float* emb  = (const float*)d_in[3];
  const float* Wq   = (const float*)d_in[4];
  const float* bq   = (const float*)d_in[5];
  const float* Wk   = (const float*)d_in[6];
  const float* bk   = (const float*)d_in[7];
  const float* Wv   = (const float*)d_in[8];
  const float* bv   = (const float*)d_in[9];
  const float* W_ih = (const float*)d_in[10];
  const float* W_hh = (const float*)d_in[11];
  const float* b_ih = (const float*)d_in[12];
  const float* b_hh = (const float*)d_in[13];
  const float* Wo   = (const float*)d_in[14];
  const float* bo   = (const float*)d_in[15];

  float* out0 = (float*)d_out;                          // log_probs [B*T, V]
  float* out1 = out0 + (size_t)B_ * T_ * V_;            // h_final [B*H]
  float* out2 = out1 + (size_t)B_ * H_;                 // attentions [B*T, S]

  // out0 doubles as scratch; k_logits overwrites it afterwards.
  float* kproj   = out0;                  // 1,048,576 floats
  float* giemb   = out0 + 1048576;        // 3,145,728
  float* emb_all = out0 + 4194304;        // 1,048,576
  float* h_glob  = out0 + 5242880;        // 16,384
  float* qgh     = out0 + 5259264;        // 65,536

  __hip_bfloat16* Hall = (__hip_bfloat16*)d_ws;                     // 2 MB
  int* flags = (int*)((char*)d_ws + (size_t)2 * 1024 * 1024);       // 1 KB

  k_emb_gather<<<2048, 256, 0, stream>>>(tgt, emb, emb_all);
  k_init<<<64, 256, 0, stream>>>(ehs, h_glob, flags);

  {
    dim3 g(H_ / 64, (B_ * S_) / 64);      // kproj: M=2048, N=512, K=512
    k_gemm_f32<<<g, 256, 0, stream>>>(enc, 512, Wk, 512, bk, kproj, 512, 512);
  }
  {
    dim3 g(1536 / 64, (T_ * B_) / 64);    // gi_emb: M=2048, N=1536, K=512
    k_gemm_f32<<<g, 256, 0, stream>>>(emb_all, 512, W_ih, 1024, b_ih, giemb, 1536, 512);
  }

  k_recur<<<NB_, 256, 0, stream>>>(Wq, W_hh, bq, kproj, enc, Wv, bv, W_ih,
                                   giemb, b_hh, h_glob, qgh, flags,
                                   out2, Hall, out1);

  {
    dim3 g((T_ * B_) / 128, V_ / 128);    // (16, 250)
    k_logits<<<g, 256, 0, stream>>>(Hall, Wo, bo, out0);
  }
  k_lsm<<<(B_ * T_), 256, 0, stream>>>(out0);
}

// Round 5
// 4437.162 us; speedup vs baseline: 1.3148x; 1.3148x over previous
//
#include <hip/hip_runtime.h>
#include <hip/hip_bf16.h>

#define B_ 32
#define S_ 64
#define H_ 512
#define V_ 32000
#define T_ 64
#define NB_ 256   // persistent grid size

typedef __bf16 bf16x8 __attribute__((ext_vector_type(8)));
typedef float f32x4 __attribute__((ext_vector_type(4)));

__device__ __forceinline__ float fast_tanh(float x) {
  float e = __expf(2.0f * x);
  return 1.0f - 2.0f / (e + 1.0f);
}
__device__ __forceinline__ float fast_sigmoid(float x) {
  return 1.0f / (1.0f + __expf(-x));
}

// ---------------- prep kernels ----------------

__global__ __launch_bounds__(256) void k_emb_gather(const int* __restrict__ target,
    const float* __restrict__ emb, float* __restrict__ emb_all) {
  int row = blockIdx.x;                 // t*32 + b
  int t = row >> 5, b = row & 31;
  int tok = (t == 0) ? 0 : target[b * T_ + t - 1];
  const float* src = emb + (size_t)tok * H_;
  float* dst = emb_all + (size_t)row * H_;
  for (int j = threadIdx.x; j < H_; j += 256) dst[j] = src[j];
}

__global__ __launch_bounds__(256) void k_init(const float* __restrict__ ehs,
    float* __restrict__ h_st0, int* __restrict__ cnt) {
  int i = blockIdx.x * 256 + threadIdx.x;
  if (i < B_ * H_) h_st0[i] = ehs[i];
  if (i == 0)
    __hip_atomic_store(cnt, 0, __ATOMIC_RELAXED, __HIP_MEMORY_SCOPE_AGENT);
}

// ---------------- generic fp32 GEMM: C[M,N] = A[M,K] @ B[N,K]^T + bias ----------------

__global__ __launch_bounds__(256) void k_gemm_f32(
    const float* __restrict__ A, int lda,
    const float* __restrict__ B, int ldb,
    const float* __restrict__ bias,
    float* __restrict__ C, int ldc, int K) {
  __shared__ float As[16][64];
  __shared__ float Bs[16][64];
  const int tid = threadIdx.x;
  const int tx = tid & 15, ty = tid >> 4;
  const int m0 = blockIdx.y * 64, n0 = blockIdx.x * 64;
  const int r = tid >> 2, c4 = (tid & 3) * 4;
  float acc[4][4] = {};
  for (int k0 = 0; k0 < K; k0 += 16) {
    const float4 av = *(const float4*)(A + (size_t)(m0 + r) * lda + k0 + c4);
    const float4 bv = *(const float4*)(B + (size_t)(n0 + r) * ldb + k0 + c4);
    __syncthreads();
    As[c4 + 0][r] = av.x; As[c4 + 1][r] = av.y; As[c4 + 2][r] = av.z; As[c4 + 3][r] = av.w;
    Bs[c4 + 0][r] = bv.x; Bs[c4 + 1][r] = bv.y; Bs[c4 + 2][r] = bv.z; Bs[c4 + 3][r] = bv.w;
    __syncthreads();
#pragma unroll
    for (int k = 0; k < 16; ++k) {
      const float4 a = *(const float4*)(&As[k][ty * 4]);
      const float4 b = *(const float4*)(&Bs[k][tx * 4]);
      const float a4[4] = {a.x, a.y, a.z, a.w};
      const float b4[4] = {b.x, b.y, b.z, b.w};
#pragma unroll
      for (int i = 0; i < 4; ++i)
#pragma unroll
        for (int j = 0; j < 4; ++j)
          acc[i][j] = fmaf(a4[i], b4[j], acc[i][j]);
    }
  }
  const float4 bb = *(const float4*)(bias + n0 + tx * 4);
#pragma unroll
  for (int i = 0; i < 4; ++i) {
    float4 o;
    o.x = acc[i][0] + bb.x; o.y = acc[i][1] + bb.y;
    o.z = acc[i][2] + bb.z; o.w = acc[i][3] + bb.w;
    *(float4*)(C + (size_t)(m0 + ty * 4 + i) * ldc + n0 + tx * 4) = o;
  }
}

// ---------------- fence-free grid barrier ----------------
// Payload protocol: producers write cross-block data with RELAXED agent-scope
// atomic stores (write-through to the device coherence point). Each wave then
// drains vmcnt, the block bumps one monotone counter (relaxed atomic add), and
// tid0 polls it with relaxed atomic loads. Consumers read payload with PLAIN
// loads from per-step rotating buffers whose lines were never cached before
// (first touch happens after the barrier -> cold miss -> coherent fetch).
// No acquire/release fences -> no L2 writeback/invalidate -> weights stay hot.

__device__ __forceinline__ void grid_bar2(int* cnt, int target) {
  asm volatile("s_waitcnt vmcnt(0)" ::: "memory");  // per-wave store drain
  __syncthreads();
  if (threadIdx.x == 0) {
    __hip_atomic_fetch_add(cnt, 1, __ATOMIC_RELAXED, __HIP_MEMORY_SCOPE_AGENT);
    while (__hip_atomic_load(cnt, __ATOMIC_RELAXED, __HIP_MEMORY_SCOPE_AGENT) < target)
      __builtin_amdgcn_s_sleep(2);
  }
  __syncthreads();
  asm volatile("" ::: "memory");                    // no load hoisting
}

// ---------------- persistent recurrence (normal launch, 256 blocks) ----------------
// Phase A: qgh_st[t][b][row] = h_st[t][b] . [Wq; W_hh][row] (+bq), weights in regs.
// Phase B: per-(js,b) attention + GRU gates -> h_st[t+1].

__global__ __launch_bounds__(256) void k_recur(
    const float* __restrict__ Wq, const float* __restrict__ W_hh,
    const float* __restrict__ bq,
    const float* __restrict__ kproj, const float* __restrict__ enc,
    const float* __restrict__ Wv, const float* __restrict__ bv,
    const float* __restrict__ W_ih, const float* __restrict__ giemb,
    const float* __restrict__ b_hh,
    float* h_st, float* qgh_st, int* cnt,
    float* __restrict__ attn_out, __hip_bfloat16* __restrict__ Hall,
    float* __restrict__ hfin) {
  const int tid = threadIdx.x;
  const int bid = blockIdx.x;

  // phase A persistent weights: row = bid*8 + r, 16-float k-slice per thread
  const int r = tid >> 5, kc = tid & 31;
  const int arow = bid * 8 + r;
  const float* wrow = (arow < 512) ? (Wq + (size_t)arow * 512)
                                   : (W_hh + (size_t)(arow - 512) * 512);
  float4 w4[4];
#pragma unroll
  for (int i = 0; i < 4; ++i) w4[i] = *(const float4*)(wrow + kc * 16 + i * 4);
  const float abias = (arow < 512) ? bq[arow] : 0.f;

  // phase B ids, XCD-aware spread (bid%8 = XCD under round-robin)
  const int gx = bid & 7, u = bid >> 3;
  const int js = (u & 3) | ((gx & 1) << 2);   // 0..7
  const int b  = (u >> 2) | ((gx >> 1) << 3); // 0..31

  __shared__ float aq_s[256];
  __shared__ float q_s[512];
  __shared__ float red[256];
  __shared__ float w_s[64];
  __shared__ float ctx_s[512];
  __shared__ float gic_s[192];

  for (int t = 0; t < T_; ++t) {
    const float* h_t  = h_st + (size_t)t * (B_ * H_);
    float* h_t1       = h_st + (size_t)(t + 1) * (B_ * H_);
    float* qgh_t      = qgh_st + (size_t)t * (B_ * 2048);

    // ---- phase A ----
    for (int bb = 0; bb < B_; ++bb) {
      const float* hb = h_t + bb * 512 + kc * 16;
      float p = 0.f;
#pragma unroll
      for (int i = 0; i < 4; ++i) {
        const float4 h4 = *(const float4*)(hb + i * 4);
        p += w4[i].x * h4.x + w4[i].y * h4.y + w4[i].z * h4.z + w4[i].w * h4.w;
      }
#pragma unroll
      for (int d = 16; d > 0; d >>= 1) p += __shfl_xor(p, d, 32);
      if (kc == 0) aq_s[r * 32 + bb] = p + abias;
    }
    __syncthreads();
    if (tid < 64) {
      const int bb = tid >> 1, hf = tid & 1;
      float v[4];
#pragma unroll
      for (int i = 0; i < 4; ++i) v[i] = aq_s[(hf * 4 + i) * 32 + bb];
      float* dst = qgh_t + bb * 2048 + bid * 8 + hf * 4;
#pragma unroll
      for (int i = 0; i < 4; ++i)
        __hip_atomic_store(dst + i, v[i], __ATOMIC_RELAXED, __HIP_MEMORY_SCOPE_AGENT);
    }
    grid_bar2(cnt, (2 * t + 1) * NB_);

    // ---- phase B ----
    q_s[tid]       = qgh_t[b * 2048 + tid];
    q_s[tid + 256] = qgh_t[b * 2048 + 256 + tid];
    __syncthreads();
    {
      const int s = tid >> 2, part = tid & 3;
      const float* kp = kproj + ((size_t)(b * S_ + s)) * H_ + part * 128;
      const float* qp = q_s + part * 128;
      const float* wp = Wv + part * 128;
      float sc = 0.f;
      for (int k = 0; k < 128; k += 4) {
        const float4 kv = *(const float4*)(kp + k);
        const float4 qv = *(const float4*)(qp + k);
        const float4 wv = *(const float4*)(wp + k);
        sc = fmaf(wv.x, fast_tanh(qv.x + kv.x), sc);
        sc = fmaf(wv.y, fast_tanh(qv.y + kv.y), sc);
        sc = fmaf(wv.z, fast_tanh(qv.z + kv.z), sc);
        sc = fmaf(wv.w, fast_tanh(qv.w + kv.w), sc);
      }
      red[tid] = sc;
    }
    __syncthreads();
    if (tid < 64) {
      float sc = red[tid * 4] + red[tid * 4 + 1] + red[tid * 4 + 2] + red[tid * 4 + 3] + bv[0];
      float m = sc;
#pragma unroll
      for (int d = 32; d > 0; d >>= 1) m = fmaxf(m, __shfl_xor(m, d, 64));
      const float e = __expf(sc - m);
      float sum = e;
#pragma unroll
      for (int d = 32; d > 0; d >>= 1) sum += __shfl_xor(sum, d, 64);
      const float w = e / sum;
      w_s[tid] = w;
      if (js == 0) attn_out[((size_t)b * T_ + t) * S_ + tid] = w;
    }
    __syncthreads();
#pragma unroll
    for (int jj = 0; jj < 2; ++jj) {
      const int j = tid + jj * 256;
      float a = 0.f;
      const float* ep = enc + (size_t)(b * S_) * H_ + j;
      for (int s = 0; s < S_; ++s) a = fmaf(w_s[s], ep[s * 512], a);
      ctx_s[j] = a;
    }
    __syncthreads();
    if (tid < 192) {
      const int gg = tid >> 6, hp = tid & 63;
      const float* wr = W_ih + (size_t)(gg * 512 + js * 64 + hp) * 1024 + 512;
      float a = 0.f;
      for (int k = 0; k < 512; k += 4) {
        const float4 wv = *(const float4*)(wr + k);
        const float4 cv = *(const float4*)(ctx_s + k);
        a += wv.x * cv.x + wv.y * cv.y + wv.z * cv.z + wv.w * cv.w;
      }
      gic_s[tid] = a;
    }
    __syncthreads();
    if (tid < 64) {
      const int hh = js * 64 + tid;
      const size_t grow = ((size_t)t * B_ + b) * 1536;
      const int gbase = b * 2048 + 512;
      const float gir = giemb[grow + hh]        + gic_s[tid];
      const float giz = giemb[grow + 512 + hh]  + gic_s[64 + tid];
      const float gin = giemb[grow + 1024 + hh] + gic_s[128 + tid];
      const float ghr = qgh_t[gbase + hh]         + b_hh[hh];
      const float ghz = qgh_t[gbase + 512 + hh]   + b_hh[512 + hh];
      const float ghn = qgh_t[gbase + 1024 + hh]  + b_hh[1024 + hh];
      const float rg = fast_sigmoid(gir + ghr);
      const float zg = fast_sigmoid(giz + ghz);
      const float ng = fast_tanh(gin + rg * ghn);
      const float ho = h_t[b * 512 + hh];        // L2-warm clean line
      const float hv = (1.f - zg) * ng + zg * ho;
      __hip_atomic_store(h_t1 + b * 512 + hh, hv, __ATOMIC_RELAXED,
                         __HIP_MEMORY_SCOPE_AGENT);
      Hall[((size_t)b * T_ + t) * H_ + hh] = __float2bfloat16(hv);
      if (t == T_ - 1) hfin[b * 512 + hh] = hv;
    }
    if (t < T_ - 1) grid_bar2(cnt, (2 * t + 2) * NB_);
  }
}

// ---------------- logits GEMM: out[m,:] = Hall[m,:] @ Wo^T + bo (bf16 MFMA) ----------------
// m = b*64+t. grid (16 m-tiles, 250 n-tiles). LDS-staged coalesced epilogue.

__global__ __launch_bounds__(256) void k_logits(
    const __hip_bfloat16* __restrict__ Hall, const float* __restrict__ Wo,
    const float* __restrict__ bo, float* __restrict__ out0) {
  __shared__ float pool[128 * 68];      // 34.8 KB; Asub/Bsub alias the front
  __hip_bfloat16* Asub = (__hip_bfloat16*)pool;           // 4096 bf16
  __hip_bfloat16* Bsub = (__hip_bfloat16*)(pool + 2048);  // 4096 bf16
  const int tid = threadIdx.x;
  const int lane = tid & 63, wave = tid >> 6;
  const int wr = wave >> 1, wc = wave & 1;
  const int m0 = blockIdx.x * 128, n0 = blockIdx.y * 128;
  f32x4 acc[4][4];
#pragma unroll
  for (int i = 0; i < 4; ++i)
#pragma unroll
    for (int j = 0; j < 4; ++j) acc[i][j] = (f32x4){0.f, 0.f, 0.f, 0.f};

  for (int k0 = 0; k0 < 512; k0 += 32) {
    uint4 a_v[2];
#pragma unroll
    for (int rr = 0; rr < 2; ++rr) {
      const int seg = tid + rr * 256;
      const int row = seg >> 2, ks8 = (seg & 3) * 8;
      a_v[rr] = *(const uint4*)(Hall + (size_t)(m0 + row) * 512 + k0 + ks8);
    }
    float4 b_v[4];
#pragma unroll
    for (int rr = 0; rr < 4; ++rr) {
      const int idx = tid + rr * 256;
      const int n = idx >> 3, kg = (idx & 7) * 4;
      b_v[rr] = *(const float4*)(Wo + (size_t)(n0 + n) * 512 + k0 + kg);
    }
    __syncthreads();
#pragma unroll
    for (int rr = 0; rr < 2; ++rr) {
      const int seg = tid + rr * 256;
      *(uint4*)(Asub + seg * 8) = a_v[rr];
    }
#pragma unroll
    for (int rr = 0; rr < 4; ++rr) {
      const int idx = tid + rr * 256;
      const int n = idx >> 3, kg = (idx & 7) * 4;
      union { __hip_bfloat16 h[4]; uint2 u; } cv;
      cv.h[0] = __float2bfloat16(b_v[rr].x);
      cv.h[1] = __float2bfloat16(b_v[rr].y);
      cv.h[2] = __float2bfloat16(b_v[rr].z);
      cv.h[3] = __float2bfloat16(b_v[rr].w);
      *(uint2*)(Bsub + n * 32 + kg) = cv.u;
    }
    __syncthreads();
    bf16x8 af[4], bfr[4];
#pragma unroll
    for (int mi = 0; mi < 4; ++mi)
      af[mi] = *(const bf16x8*)(Asub + (wr * 64 + mi * 16 + (lane & 15)) * 32 + (lane >> 4) * 8);
#pragma unroll
    for (int ni = 0; ni < 4; ++ni)
      bfr[ni] = *(const bf16x8*)(Bsub + (wc * 64 + ni * 16 + (lane & 15)) * 32 + (lane >> 4) * 8);
#pragma unroll
    for (int mi = 0; mi < 4; ++mi)
#pragma unroll
      for (int ni = 0; ni < 4; ++ni)
        acc[mi][ni] = __builtin_amdgcn_mfma_f32_16x16x32_bf16(af[mi], bfr[ni], acc[mi][ni], 0, 0, 0);
  }

  // epilogue: stage each 128x64 half in LDS, then 256B-contiguous float4 stores
  float* Cs = pool;
  const int r4 = (lane >> 4) * 4, cc = lane & 15;
#pragma unroll
  for (int hf = 0; hf < 2; ++hf) {
    __syncthreads();
    if (wc == hf) {
#pragma unroll
      for (int ni = 0; ni < 4; ++ni) {
        const float bias = bo[n0 + hf * 64 + ni * 16 + cc];
#pragma unroll
        for (int mi = 0; mi < 4; ++mi)
#pragma unroll
          for (int i = 0; i < 4; ++i)
            Cs[(wr * 64 + mi * 16 + r4 + i) * 68 + ni * 16 + cc] = acc[mi][ni][i] + bias;
      }
    }
    __syncthreads();
    const int rowp = tid >> 4, colg = tid & 15;
#pragma unroll
    for (int pass = 0; pass < 8; ++pass) {
      const int row = pass * 16 + rowp;
      const float4 v = *(const float4*)(Cs + row * 68 + colg * 4);
      *(float4*)(out0 + (size_t)(m0 + row) * V_ + n0 + hf * 64 + colg * 4) = v;
    }
  }
}

// ---------------- in-place log_softmax over V, one row per block ----------------

__global__ __launch_bounds__(256) void k_lsm(float* __restrict__ out0) {
  __shared__ float rm[256];
  __shared__ float rs[256];
  const int row = blockIdx.x, tid = threadIdx.x;
  float4* p = (float4*)(out0 + (size_t)row * V_);
  float m = -INFINITY, s = 0.f;
  for (int i = tid; i < V_ / 4; i += 256) {
    const float4 v = p[i];
    const float mx = fmaxf(fmaxf(v.x, v.y), fmaxf(v.z, v.w));
    if (mx > m) { s *= __expf(m - mx); m = mx; }
    s += __expf(v.x - m) + __expf(v.y - m) + __expf(v.z - m) + __expf(v.w - m);
  }
  rm[tid] = m; rs[tid] = s;
  __syncthreads();
  for (int off = 128; off > 0; off >>= 1) {
    if (tid < off) {
      const float m2 = rm[tid + off], s2 = rs[tid + off];
      const float M = fmaxf(rm[tid], m2);
      rs[tid] = rs[tid] * __expf(rm[tid] - M) + s2 * __expf(m2 - M);
      rm[tid] = M;
    }
    __syncthreads();
  }
  const float lse = rm[0] + __logf(rs[0]);
  for (int i = tid; i < V_ / 4; i += 256) {
    float4 v = p[i];
    v.x -= lse; v.y -= lse; v.z -= lse; v.w -= lse;
    p[i] = v;
  }
}

// ---------------- host ----------------

extern "C" void kernel_launch(void* const* d_in, const int* in_sizes, int n_in,
                              void* d_out, int out_size, void* d_ws, size_t ws_size,
                              hipStream_t stream) {
  (void)in_sizes; (void)n_in; (void)out_size; (void)ws_size;
  const float* enc  = (const float*)d_in[0];
  const float* ehs  = (const float*)d_in[1];
  const int*   tgt  = (const int*)d_in[2];
  const float* emb  = (const float*)d_in[3];
  const float* Wq   = (const float*)d_in[4];
  const float* bq   = (const float*)d_in[5];
  const float* Wk   = (const float*)d_in[6];
  const float* bk   = (const float*)d_in[7];
  const float* Wv   = (const float*)d_in[8];
  const float* bv   = (const float*)d_in[9];
  const float* W_ih = (const float*)d_in[10];
  const float* W_hh = (const float*)d_in[11];
  const float* b_ih = (const float*)d_in[12];
  const float* b_hh = (const float*)d_in[13];
  const float* Wo   = (const float*)d_in[14];
  const float* bo   = (const float*)d_in[15];

  float* out0 = (float*)d_out;                          // log_probs [B*T, V]
  float* out1 = out0 + (size_t)B_ * T_ * V_;            // h_final [B*H]
  float* out2 = out1 + (size_t)B_ * H_;                 // attentions [B*T, S]

  // out0 doubles as scratch; k_logits overwrites it afterwards.
  float* kproj   = out0;                  // [0, 1048576)
  float* giemb   = out0 + 1048576;        // [1048576, 4194304)
  float* emb_all = out0 + 4194304;        // [4194304, 5242880)
  float* qgh_st  = out0 + 5242880;        // 64 steps x 65536 = [.., 9437184)
  float* h_st    = out0 + 9437184;        // 65 steps x 16384 = [.., 10502144)

  __hip_bfloat16* Hall = (__hip_bfloat16*)d_ws;                     // 2 MB
  int* cnt = (int*)((char*)d_ws + (size_t)2 * 1024 * 1024);         // 4 B

  k_emb_gather<<<2048, 256, 0, stream>>>(tgt, emb, emb_all);
  k_init<<<64, 256, 0, stream>>>(ehs, h_st, cnt);

  {
    dim3 g(H_ / 64, (B_ * S_) / 64);      // kproj: M=2048, N=512, K=512
    k_gemm_f32<<<g, 256, 0, stream>>>(enc, 512, Wk, 512, bk, kproj, 512, 512);
  }
  {
    dim3 g(1536 / 64, (T_ * B_) / 64);    // gi_emb: M=2048, N=1536, K=512
    k_gemm_f32<<<g, 256, 0, stream>>>(emb_all, 512, W_ih, 1024, b_ih, giemb, 1536, 512);
  }

  k_recur<<<NB_, 256, 0, stream>>>(Wq, W_hh, bq, kproj, enc, Wv, bv, W_ih,
                                   giemb, b_hh, h_st, qgh_st, cnt,
                                   out2, Hall, out1);

  {
    dim3 g((T_ * B_) / 128, V_ / 128);    // (16, 250)
    k_logits<<<g, 256, 0, stream>>>(Hall, Wo, bo, out0);
  }
  k_lsm<<<(B_ * T_), 256, 0, stream>>>(out0);
}

// Round 6
// 4108.512 us; speedup vs baseline: 1.4200x; 1.0800x over previous
//
#include <hip/hip_runtime.h>
#include <hip/hip_bf16.h>

#define B_ 32
#define S_ 64
#define H_ 512
#define V_ 32000
#define T_ 64
#define NB_ 256   // persistent grid size

typedef __bf16 bf16x8 __attribute__((ext_vector_type(8)));
typedef float f32x4 __attribute__((ext_vector_type(4)));

__device__ __forceinline__ float fast_tanh(float x) {
  float e = __expf(2.0f * x);
  return 1.0f - 2.0f / (e + 1.0f);
}
__device__ __forceinline__ float fast_sigmoid(float x) {
  return 1.0f / (1.0f + __expf(-x));
}

// ---------------- prep kernels ----------------

__global__ __launch_bounds__(256) void k_emb_gather(const int* __restrict__ target,
    const float* __restrict__ emb, float* __restrict__ emb_all) {
  int row = blockIdx.x;                 // t*32 + b
  int t = row >> 5, b = row & 31;
  int tok = (t == 0) ? 0 : target[b * T_ + t - 1];
  const float* src = emb + (size_t)tok * H_;
  float* dst = emb_all + (size_t)row * H_;
  for (int j = threadIdx.x; j < H_; j += 256) dst[j] = src[j];
}

__global__ __launch_bounds__(256) void k_init(const float* __restrict__ ehs,
    float* __restrict__ h_st0, int* __restrict__ flags) {
  int i = blockIdx.x * 256 + threadIdx.x;
  if (i < B_ * H_) h_st0[i] = ehs[i];
  if (i < NB_ + 16)   // 256 block flags + 16 group flags
    __hip_atomic_store(&flags[i], 0, __ATOMIC_RELAXED, __HIP_MEMORY_SCOPE_AGENT);
}

// ---------------- generic fp32 GEMM: C[M,N] = A[M,K] @ B[N,K]^T + bias ----------------

__global__ __launch_bounds__(256) void k_gemm_f32(
    const float* __restrict__ A, int lda,
    const float* __restrict__ B, int ldb,
    const float* __restrict__ bias,
    float* __restrict__ C, int ldc, int K) {
  __shared__ float As[16][64];
  __shared__ float Bs[16][64];
  const int tid = threadIdx.x;
  const int tx = tid & 15, ty = tid >> 4;
  const int m0 = blockIdx.y * 64, n0 = blockIdx.x * 64;
  const int r = tid >> 2, c4 = (tid & 3) * 4;
  float acc[4][4] = {};
  for (int k0 = 0; k0 < K; k0 += 16) {
    const float4 av = *(const float4*)(A + (size_t)(m0 + r) * lda + k0 + c4);
    const float4 bv = *(const float4*)(B + (size_t)(n0 + r) * ldb + k0 + c4);
    __syncthreads();
    As[c4 + 0][r] = av.x; As[c4 + 1][r] = av.y; As[c4 + 2][r] = av.z; As[c4 + 3][r] = av.w;
    Bs[c4 + 0][r] = bv.x; Bs[c4 + 1][r] = bv.y; Bs[c4 + 2][r] = bv.z; Bs[c4 + 3][r] = bv.w;
    __syncthreads();
#pragma unroll
    for (int k = 0; k < 16; ++k) {
      const float4 a = *(const float4*)(&As[k][ty * 4]);
      const float4 b = *(const float4*)(&Bs[k][tx * 4]);
      const float a4[4] = {a.x, a.y, a.z, a.w};
      const float b4[4] = {b.x, b.y, b.z, b.w};
#pragma unroll
      for (int i = 0; i < 4; ++i)
#pragma unroll
        for (int j = 0; j < 4; ++j)
          acc[i][j] = fmaf(a4[i], b4[j], acc[i][j]);
    }
  }
  const float4 bb = *(const float4*)(bias + n0 + tx * 4);
#pragma unroll
  for (int i = 0; i < 4; ++i) {
    float4 o;
    o.x = acc[i][0] + bb.x; o.y = acc[i][1] + bb.y;
    o.z = acc[i][2] + bb.z; o.w = acc[i][3] + bb.w;
    *(float4*)(C + (size_t)(m0 + ty * 4 + i) * ldc + n0 + tx * 4) = o;
  }
}

// ---------------- fence-free TWO-LEVEL grid barrier ----------------
// Same payload protocol as r5 (relaxed write-through stores + rotating buffers
// + vmcnt(0) drain + first-touch cold reads). Barrier itself is now
// contention-free: per-block flag STORES (no RMW), 16 masters aggregate their
// group's 64B flag line, everyone polls the single gflags line with one
// coalesced 16-lane read per sweep.

__device__ __forceinline__ void grid_bar3(int* flags, int target) {
  int* gflags = flags + NB_;            // 16 ints, own cache line
  asm volatile("s_waitcnt vmcnt(0)" ::: "memory");  // payload stores acked
  __syncthreads();
  const int tid = threadIdx.x;
  const int bid = blockIdx.x;
  if (tid == 0)
    __hip_atomic_store(&flags[bid], target, __ATOMIC_RELAXED,
                       __HIP_MEMORY_SCOPE_AGENT);
  if (bid < 16) {
    // master: wave 0 lanes 0..15 poll this group's 16 flags (one 64B line)
    if (tid < 16) {
      while (__hip_atomic_load(&flags[bid * 16 + tid], __ATOMIC_RELAXED,
                               __HIP_MEMORY_SCOPE_AGENT) < target)
        __builtin_amdgcn_s_sleep(4);
    }
    // wave exits loop only when all 16 lanes done; tid==0 store follows in
    // program order -> gflag implies whole group arrived.
    if (tid == 0)
      __hip_atomic_store(&gflags[bid], target, __ATOMIC_RELAXED,
                         __HIP_MEMORY_SCOPE_AGENT);
  }
  if (tid < 16) {
    while (__hip_atomic_load(&gflags[tid], __ATOMIC_RELAXED,
                             __HIP_MEMORY_SCOPE_AGENT) < target)
      __builtin_amdgcn_s_sleep(8);
  }
  __syncthreads();
  asm volatile("" ::: "memory");        // no load hoisting above the barrier
}

// ---------------- persistent recurrence (normal launch, 256 blocks) ----------------
// Phase A: qgh_st[t][b][row] = h_st[t][b] . [Wq; W_hh][row] (+bq), weights in regs.
// Phase B: per-(js,b) attention + GRU gates -> h_st[t+1].

__global__ __launch_bounds__(256) void k_recur(
    const float* __restrict__ Wq, const float* __restrict__ W_hh,
    const float* __restrict__ bq,
    const float* __restrict__ kproj, const float* __restrict__ enc,
    const float* __restrict__ Wv, const float* __restrict__ bv,
    const float* __restrict__ W_ih, const float* __restrict__ giemb,
    const float* __restrict__ b_hh,
    float* h_st, float* qgh_st, int* flags,
    float* __restrict__ attn_out, __hip_bfloat16* __restrict__ Hall,
    float* __restrict__ hfin) {
  const int tid = threadIdx.x;
  const int bid = blockIdx.x;

  // phase A persistent weights: row = bid*8 + r, 16-float k-slice per thread
  const int r = tid >> 5, kc = tid & 31;
  const int arow = bid * 8 + r;
  const float* wrow = (arow < 512) ? (Wq + (size_t)arow * 512)
                                   : (W_hh + (size_t)(arow - 512) * 512);
  float4 w4[4];
#pragma unroll
  for (int i = 0; i < 4; ++i) w4[i] = *(const float4*)(wrow + kc * 16 + i * 4);
  const float abias = (arow < 512) ? bq[arow] : 0.f;

  // phase B ids, XCD-aware spread (bid%8 = XCD under round-robin)
  const int gx = bid & 7, u = bid >> 3;
  const int js = (u & 3) | ((gx & 1) << 2);   // 0..7
  const int b  = (u >> 2) | ((gx >> 1) << 3); // 0..31

  __shared__ float aq_s[256];
  __shared__ float q_s[512];
  __shared__ float red[256];
  __shared__ float w_s[64];
  __shared__ float ctx_s[512];
  __shared__ float gic_s[192];

  for (int t = 0; t < T_; ++t) {
    const float* h_t  = h_st + (size_t)t * (B_ * H_);
    float* h_t1       = h_st + (size_t)(t + 1) * (B_ * H_);
    float* qgh_t      = qgh_st + (size_t)t * (B_ * 2048);

    // ---- phase A ----
    for (int bb = 0; bb < B_; ++bb) {
      const float* hb = h_t + bb * 512 + kc * 16;
      float p = 0.f;
#pragma unroll
      for (int i = 0; i < 4; ++i) {
        const float4 h4 = *(const float4*)(hb + i * 4);
        p += w4[i].x * h4.x + w4[i].y * h4.y + w4[i].z * h4.z + w4[i].w * h4.w;
      }
#pragma unroll
      for (int d = 16; d > 0; d >>= 1) p += __shfl_xor(p, d, 32);
      if (kc == 0) aq_s[r * 32 + bb] = p + abias;
    }
    __syncthreads();
    if (tid < 64) {
      const int bb = tid >> 1, hf = tid & 1;
      float v[4];
#pragma unroll
      for (int i = 0; i < 4; ++i) v[i] = aq_s[(hf * 4 + i) * 32 + bb];
      float* dst = qgh_t + bb * 2048 + bid * 8 + hf * 4;
#pragma unroll
      for (int i = 0; i < 4; ++i)
        __hip_atomic_store(dst + i, v[i], __ATOMIC_RELAXED, __HIP_MEMORY_SCOPE_AGENT);
    }
    grid_bar3(flags, 2 * t + 1);

    // ---- phase B ----
    q_s[tid]       = qgh_t[b * 2048 + tid];
    q_s[tid + 256] = qgh_t[b * 2048 + 256 + tid];
    __syncthreads();
    {
      const int s = tid >> 2, part = tid & 3;
      const float* kp = kproj + ((size_t)(b * S_ + s)) * H_ + part * 128;
      const float* qp = q_s + part * 128;
      const float* wp = Wv + part * 128;
      float sc = 0.f;
      for (int k = 0; k < 128; k += 4) {
        const float4 kv = *(const float4*)(kp + k);
        const float4 qv = *(const float4*)(qp + k);
        const float4 wv = *(const float4*)(wp + k);
        sc = fmaf(wv.x, fast_tanh(qv.x + kv.x), sc);
        sc = fmaf(wv.y, fast_tanh(qv.y + kv.y), sc);
        sc = fmaf(wv.z, fast_tanh(qv.z + kv.z), sc);
        sc = fmaf(wv.w, fast_tanh(qv.w + kv.w), sc);
      }
      red[tid] = sc;
    }
    __syncthreads();
    if (tid < 64) {
      float sc = red[tid * 4] + red[tid * 4 + 1] + red[tid * 4 + 2] + red[tid * 4 + 3] + bv[0];
      float m = sc;
#pragma unroll
      for (int d = 32; d > 0; d >>= 1) m = fmaxf(m, __shfl_xor(m, d, 64));
      const float e = __expf(sc - m);
      float sum = e;
#pragma unroll
      for (int d = 32; d > 0; d >>= 1) sum += __shfl_xor(sum, d, 64);
      const float w = e / sum;
      w_s[tid] = w;
      if (js == 0) attn_out[((size_t)b * T_ + t) * S_ + tid] = w;
    }
    __syncthreads();
#pragma unroll
    for (int jj = 0; jj < 2; ++jj) {
      const int j = tid + jj * 256;
      float a = 0.f;
      const float* ep = enc + (size_t)(b * S_) * H_ + j;
      for (int s = 0; s < S_; ++s) a = fmaf(w_s[s], ep[s * 512], a);
      ctx_s[j] = a;
    }
    __syncthreads();
    if (tid < 192) {
      const int gg = tid >> 6, hp = tid & 63;
      const float* wr = W_ih + (size_t)(gg * 512 + js * 64 + hp) * 1024 + 512;
      float a = 0.f;
      for (int k = 0; k < 512; k += 4) {
        const float4 wv = *(const float4*)(wr + k);
        const float4 cv = *(const float4*)(ctx_s + k);
        a += wv.x * cv.x + wv.y * cv.y + wv.z * cv.z + wv.w * cv.w;
      }
      gic_s[tid] = a;
    }
    __syncthreads();
    if (tid < 64) {
      const int hh = js * 64 + tid;
      const size_t grow = ((size_t)t * B_ + b) * 1536;
      const int gbase = b * 2048 + 512;
      const float gir = giemb[grow + hh]        + gic_s[tid];
      const float giz = giemb[grow + 512 + hh]  + gic_s[64 + tid];
      const float gin = giemb[grow + 1024 + hh] + gic_s[128 + tid];
      const float ghr = qgh_t[gbase + hh]         + b_hh[hh];
      const float ghz = qgh_t[gbase + 512 + hh]   + b_hh[512 + hh];
      const float ghn = qgh_t[gbase + 1024 + hh]  + b_hh[1024 + hh];
      const float rg = fast_sigmoid(gir + ghr);
      const float zg = fast_sigmoid(giz + ghz);
      const float ng = fast_tanh(gin + rg * ghn);
      const float ho = h_t[b * 512 + hh];        // L2-warm clean line
      const float hv = (1.f - zg) * ng + zg * ho;
      __hip_atomic_store(h_t1 + b * 512 + hh, hv, __ATOMIC_RELAXED,
                         __HIP_MEMORY_SCOPE_AGENT);
      Hall[((size_t)b * T_ + t) * H_ + hh] = __float2bfloat16(hv);
      if (t == T_ - 1) hfin[b * 512 + hh] = hv;
    }
    if (t < T_ - 1) grid_bar3(flags, 2 * t + 2);
  }
}

// ---------------- logits GEMM: out[m,:] = Hall[m,:] @ Wo^T + bo (bf16 MFMA) ----------------
// m = b*64+t. grid (16 m-tiles, 250 n-tiles). LDS-staged coalesced epilogue.

__global__ __launch_bounds__(256) void k_logits(
    const __hip_bfloat16* __restrict__ Hall, const float* __restrict__ Wo,
    const float* __restrict__ bo, float* __restrict__ out0) {
  __shared__ float pool[128 * 68];      // 34.8 KB; Asub/Bsub alias the front
  __hip_bfloat16* Asub = (__hip_bfloat16*)pool;           // 4096 bf16
  __hip_bfloat16* Bsub = (__hip_bfloat16*)(pool + 2048);  // 4096 bf16
  const int tid = threadIdx.x;
  const int lane = tid & 63, wave = tid >> 6;
  const int wr = wave >> 1, wc = wave & 1;
  const int m0 = blockIdx.x * 128, n0 = blockIdx.y * 128;
  f32x4 acc[4][4];
#pragma unroll
  for (int i = 0; i < 4; ++i)
#pragma unroll
    for (int j = 0; j < 4; ++j) acc[i][j] = (f32x4){0.f, 0.f, 0.f, 0.f};

  for (int k0 = 0; k0 < 512; k0 += 32) {
    uint4 a_v[2];
#pragma unroll
    for (int rr = 0; rr < 2; ++rr) {
      const int seg = tid + rr * 256;
      const int row = seg >> 2, ks8 = (seg & 3) * 8;
      a_v[rr] = *(const uint4*)(Hall + (size_t)(m0 + row) * 512 + k0 + ks8);
    }
    float4 b_v[4];
#pragma unroll
    for (int rr = 0; rr < 4; ++rr) {
      const int idx = tid + rr * 256;
      const int n = idx >> 3, kg = (idx & 7) * 4;
      b_v[rr] = *(const float4*)(Wo + (size_t)(n0 + n) * 512 + k0 + kg);
    }
    __syncthreads();
#pragma unroll
    for (int rr = 0; rr < 2; ++rr) {
      const int seg = tid + rr * 256;
      *(uint4*)(Asub + seg * 8) = a_v[rr];
    }
#pragma unroll
    for (int rr = 0; rr < 4; ++rr) {
      const int idx = tid + rr * 256;
      const int n = idx >> 3, kg = (idx & 7) * 4;
      union { __hip_bfloat16 h[4]; uint2 u; } cv;
      cv.h[0] = __float2bfloat16(b_v[rr].x);
      cv.h[1] = __float2bfloat16(b_v[rr].y);
      cv.h[2] = __float2bfloat16(b_v[rr].z);
      cv.h[3] = __float2bfloat16(b_v[rr].w);
      *(uint2*)(Bsub + n * 32 + kg) = cv.u;
    }
    __syncthreads();
    bf16x8 af[4], bfr[4];
#pragma unroll
    for (int mi = 0; mi < 4; ++mi)
      af[mi] = *(const bf16x8*)(Asub + (wr * 64 + mi * 16 + (lane & 15)) * 32 + (lane >> 4) * 8);
#pragma unroll
    for (int ni = 0; ni < 4; ++ni)
      bfr[ni] = *(const bf16x8*)(Bsub + (wc * 64 + ni * 16 + (lane & 15)) * 32 + (lane >> 4) * 8);
#pragma unroll
    for (int mi = 0; mi < 4; ++mi)
#pragma unroll
      for (int ni = 0; ni < 4; ++ni)
        acc[mi][ni] = __builtin_amdgcn_mfma_f32_16x16x32_bf16(af[mi], bfr[ni], acc[mi][ni], 0, 0, 0);
  }

  // epilogue: stage each 128x64 half in LDS, then 256B-contiguous float4 stores
  float* Cs = pool;
  const int r4 = (lane >> 4) * 4, cc = lane & 15;
#pragma unroll
  for (int hf = 0; hf < 2; ++hf) {
    __syncthreads();
    if (wc == hf) {
#pragma unroll
      for (int ni = 0; ni < 4; ++ni) {
        const float bias = bo[n0 + hf * 64 + ni * 16 + cc];
#pragma unroll
        for (int mi = 0; mi < 4; ++mi)
#pragma unroll
          for (int i = 0; i < 4; ++i)
            Cs[(wr * 64 + mi * 16 + r4 + i) * 68 + ni * 16 + cc] = acc[mi][ni][i] + bias;
      }
    }
    __syncthreads();
    const int rowp = tid >> 4, colg = tid & 15;
#pragma unroll
    for (int pass = 0; pass < 8; ++pass) {
      const int row = pass * 16 + rowp;
      const float4 v = *(const float4*)(Cs + row * 68 + colg * 4);
      *(float4*)(out0 + (size_t)(m0 + row) * V_ + n0 + hf * 64 + colg * 4) = v;
    }
  }
}

// ---------------- in-place log_softmax over V, one row per block ----------------

__global__ __launch_bounds__(256) void k_lsm(float* __restrict__ out0) {
  __shared__ float rm[256];
  __shared__ float rs[256];
  const int row = blockIdx.x, tid = threadIdx.x;
  float4* p = (float4*)(out0 + (size_t)row * V_);
  float m = -INFINITY, s = 0.f;
  for (int i = tid; i < V_ / 4; i += 256) {
    const float4 v = p[i];
    const float mx = fmaxf(fmaxf(v.x, v.y), fmaxf(v.z, v.w));
    if (mx > m) { s *= __expf(m - mx); m = mx; }
    s += __expf(v.x - m) + __expf(v.y - m) + __expf(v.z - m) + __expf(v.w - m);
  }
  rm[tid] = m; rs[tid] = s;
  __syncthreads();
  for (int off = 128; off > 0; off >>= 1) {
    if (tid < off) {
      const float m2 = rm[tid + off], s2 = rs[tid + off];
      const float M = fmaxf(rm[tid], m2);
      rs[tid] = rs[tid] * __expf(rm[tid] - M) + s2 * __expf(m2 - M);
      rm[tid] = M;
    }
    __syncthreads();
  }
  const float lse = rm[0] + __logf(rs[0]);
  for (int i = tid; i < V_ / 4; i += 256) {
    float4 v = p[i];
    v.x -= lse; v.y -= lse; v.z -= lse; v.w -= lse;
    p[i] = v;
  }
}

// ---------------- host ----------------

extern "C" void kernel_launch(void* const* d_in, const int* in_sizes, int n_in,
                              void* d_out, int out_size, void* d_ws, size_t ws_size,
                              hipStream_t stream) {
  (void)in_sizes; (void)n_in; (void)out_size; (void)ws_size;
  const float* enc  = (const float*)d_in[0];
  const float* ehs  = (const float*)d_in[1];
  const int*   tgt  = (const int*)d_in[2];
  const float* emb  = (const float*)d_in[3];
  const float* Wq   = (const float*)d_in[4];
  const float* bq   = (const float*)d_in[5];
  const float* Wk   = (const float*)d_in[6];
  const float* bk   = (const float*)d_in[7];
  const float* Wv   = (const float*)d_in[8];
  const float* bv   = (const float*)d_in[9];
  const float* W_ih = (const float*)d_in[10];
  const float* W_hh = (const float*)d_in[11];
  const float* b_ih = (const float*)d_in[12];
  const float* b_hh = (const float*)d_in[13];
  const float* Wo   = (const float*)d_in[14];
  const float* bo   = (const float*)d_in[15];

  float* out0 = (float*)d_out;                          // log_probs [B*T, V]
  float* out1 = out0 + (size_t)B_ * T_ * V_;            // h_final [B*H]
  float* out2 = out1 + (size_t)B_ * H_;                 // attentions [B*T, S]

  // out0 doubles as scratch; k_logits overwrites it afterwards.
  float* kproj   = out0;                  // [0, 1048576)
  float* giemb   = out0 + 1048576;        // [1048576, 4194304)
  float* emb_all = out0 + 4194304;        // [4194304, 5242880)
  float* qgh_st  = out0 + 5242880;        // 64 steps x 65536 = [.., 9437184)
  float* h_st    = out0 + 9437184;        // 65 steps x 16384 = [.., 10502144)

  __hip_bfloat16* Hall = (__hip_bfloat16*)d_ws;                     // 2 MB
  int* flags = (int*)((char*)d_ws + (size_t)2 * 1024 * 1024);       // 272 ints

  k_emb_gather<<<2048, 256, 0, stream>>>(tgt, emb, emb_all);
  k_init<<<64, 256, 0, stream>>>(ehs, h_st, flags);

  {
    dim3 g(H_ / 64, (B_ * S_) / 64);      // kproj: M=2048, N=512, K=512
    k_gemm_f32<<<g, 256, 0, stream>>>(enc, 512, Wk, 512, bk, kproj, 512, 512);
  }
  {
    dim3 g(1536 / 64, (T_ * B_) / 64);    // gi_emb: M=2048, N=1536, K=512
    k_gemm_f32<<<g, 256, 0, stream>>>(emb_all, 512, W_ih, 1024, b_ih, giemb, 1536, 512);
  }

  k_recur<<<NB_, 256, 0, stream>>>(Wq, W_hh, bq, kproj, enc, Wv, bv, W_ih,
                                   giemb, b_hh, h_st, qgh_st, flags,
                                   out2, Hall, out1);

  {
    dim3 g((T_ * B_) / 128, V_ / 128);    // (16, 250)
    k_logits<<<g, 256, 0, stream>>>(Hall, Wo, bo, out0);
  }
  k_lsm<<<(B_ * T_), 256, 0, stream>>>(out0);
}

// Round 7
// 1841.788 us; speedup vs baseline: 3.1676x; 2.2307x over previous
//
#include <hip/hip_runtime.h>
#include <hip/hip_bf16.h>

#define B_ 32
#define S_ 64
#define H_ 512
#define V_ 32000
#define T_ 64

typedef __bf16 bf16x8 __attribute__((ext_vector_type(8)));
typedef float f32x4 __attribute__((ext_vector_type(4)));

__device__ __forceinline__ float fast_tanh(float x) {
  float e = __expf(2.0f * x);
  return 1.0f - 2.0f / (e + 1.0f);
}
__device__ __forceinline__ float fast_sigmoid(float x) {
  return 1.0f / (1.0f + __expf(-x));
}

// ---------------- prep kernels ----------------

// gather previous-token embeddings directly to bf16 (GEMM A-operand)
__global__ __launch_bounds__(256) void k_emb_gather(const int* __restrict__ target,
    const float* __restrict__ emb, __hip_bfloat16* __restrict__ emb_bf) {
  int row = blockIdx.x;                 // t*32 + b
  int t = row >> 5, b = row & 31;
  int tok = (t == 0) ? 0 : target[b * T_ + t - 1];
  const float* src = emb + (size_t)tok * H_;
  __hip_bfloat16* dst = emb_bf + (size_t)row * H_;
  for (int jj = threadIdx.x; jj < H_; jj += 256) dst[jj] = __float2bfloat16(src[jj]);
}

__global__ __launch_bounds__(256) void k_cvt_dense(const float* __restrict__ src,
    __hip_bfloat16* __restrict__ dst, int n4) {
  int i = blockIdx.x * 256 + threadIdx.x;
  if (i < n4) {
    const float4 v = ((const float4*)src)[i];
    union { __hip_bfloat16 h[4]; uint2 u; } cv;
    cv.h[0] = __float2bfloat16(v.x); cv.h[1] = __float2bfloat16(v.y);
    cv.h[2] = __float2bfloat16(v.z); cv.h[3] = __float2bfloat16(v.w);
    *(uint2*)(dst + (size_t)i * 4) = cv.u;
  }
}

// W_ihc (= W_ih[:, 512:1024]) -> packed bf16 [1536][512]
__global__ __launch_bounds__(128) void k_cvt_wihc(const float* __restrict__ W_ih,
    __hip_bfloat16* __restrict__ dst) {
  const int row = blockIdx.x;           // 0..1535
  const int c4 = threadIdx.x * 4;
  const float4 v = *(const float4*)(W_ih + (size_t)row * 1024 + 512 + c4);
  union { __hip_bfloat16 h[4]; uint2 u; } cv;
  cv.h[0] = __float2bfloat16(v.x); cv.h[1] = __float2bfloat16(v.y);
  cv.h[2] = __float2bfloat16(v.z); cv.h[3] = __float2bfloat16(v.w);
  *(uint2*)(dst + (size_t)row * 512 + c4) = cv.u;
}

__global__ __launch_bounds__(256) void k_init(const float* __restrict__ ehs,
    float* __restrict__ h_st0, int* __restrict__ flags) {
  int i = blockIdx.x * 256 + threadIdx.x;
  if (i < B_ * H_) h_st0[i] = ehs[i];
  if (i < 1024)
    __hip_atomic_store(&flags[i], 0, __ATOMIC_RELAXED, __HIP_MEMORY_SCOPE_AGENT);
}

// ---------------- generic bf16-MFMA GEMM: C[M,N] = A[M,K] @ B[N,K]^T (+bias) ----------------
// A bf16 (lda), B fp32 cast inline (ldb), C fp32 (ldc). grid (N/128, M/128), 256 thr.

__global__ __launch_bounds__(256) void k_gemm_bf16(
    const __hip_bfloat16* __restrict__ A, int lda,
    const float* __restrict__ B, int ldb,
    const float* __restrict__ bias,
    float* __restrict__ C, int ldc, int K) {
  __shared__ float pool[128 * 68];
  __hip_bfloat16* Asub = (__hip_bfloat16*)pool;
  __hip_bfloat16* Bsub = (__hip_bfloat16*)(pool + 2048);
  const int tid = threadIdx.x;
  const int lane = tid & 63, wave = tid >> 6;
  const int wr = wave >> 1, wc = wave & 1;
  const int n0 = blockIdx.x * 128, m0 = blockIdx.y * 128;
  f32x4 acc[4][4];
#pragma unroll
  for (int i = 0; i < 4; ++i)
#pragma unroll
    for (int jj = 0; jj < 4; ++jj) acc[i][jj] = (f32x4){0.f, 0.f, 0.f, 0.f};

  for (int k0 = 0; k0 < K; k0 += 32) {
    uint4 a_v[2];
#pragma unroll
    for (int rr = 0; rr < 2; ++rr) {
      const int seg = tid + rr * 256;
      const int row = seg >> 2, ks8 = (seg & 3) * 8;
      a_v[rr] = *(const uint4*)(A + (size_t)(m0 + row) * lda + k0 + ks8);
    }
    float4 b_v[4];
#pragma unroll
    for (int rr = 0; rr < 4; ++rr) {
      const int idx = tid + rr * 256;
      const int n = idx >> 3, kg = (idx & 7) * 4;
      b_v[rr] = *(const float4*)(B + (size_t)(n0 + n) * ldb + k0 + kg);
    }
    __syncthreads();
#pragma unroll
    for (int rr = 0; rr < 2; ++rr) {
      const int seg = tid + rr * 256;
      *(uint4*)(Asub + seg * 8) = a_v[rr];
    }
#pragma unroll
    for (int rr = 0; rr < 4; ++rr) {
      const int idx = tid + rr * 256;
      const int n = idx >> 3, kg = (idx & 7) * 4;
      union { __hip_bfloat16 h[4]; uint2 u; } cv;
      cv.h[0] = __float2bfloat16(b_v[rr].x);
      cv.h[1] = __float2bfloat16(b_v[rr].y);
      cv.h[2] = __float2bfloat16(b_v[rr].z);
      cv.h[3] = __float2bfloat16(b_v[rr].w);
      *(uint2*)(Bsub + n * 32 + kg) = cv.u;
    }
    __syncthreads();
    bf16x8 af[4], bfr[4];
#pragma unroll
    for (int mi = 0; mi < 4; ++mi)
      af[mi] = *(const bf16x8*)(Asub + (wr * 64 + mi * 16 + (lane & 15)) * 32 + (lane >> 4) * 8);
#pragma unroll
    for (int ni = 0; ni < 4; ++ni)
      bfr[ni] = *(const bf16x8*)(Bsub + (wc * 64 + ni * 16 + (lane & 15)) * 32 + (lane >> 4) * 8);
#pragma unroll
    for (int mi = 0; mi < 4; ++mi)
#pragma unroll
      for (int ni = 0; ni < 4; ++ni)
        acc[mi][ni] = __builtin_amdgcn_mfma_f32_16x16x32_bf16(af[mi], bfr[ni], acc[mi][ni], 0, 0, 0);
  }

  float* Cs = pool;
  const int r4 = (lane >> 4) * 4, cc = lane & 15;
#pragma unroll
  for (int hf = 0; hf < 2; ++hf) {
    __syncthreads();
    if (wc == hf) {
#pragma unroll
      for (int ni = 0; ni < 4; ++ni) {
        const float bb = bias ? bias[n0 + hf * 64 + ni * 16 + cc] : 0.f;
#pragma unroll
        for (int mi = 0; mi < 4; ++mi)
#pragma unroll
          for (int i = 0; i < 4; ++i)
            Cs[(wr * 64 + mi * 16 + r4 + i) * 68 + ni * 16 + cc] = acc[mi][ni][i] + bb;
      }
    }
    __syncthreads();
    const int rowp = tid >> 4, colg = tid & 15;
#pragma unroll
    for (int pass = 0; pass < 8; ++pass) {
      const int row = pass * 16 + rowp;
      const float4 v = *(const float4*)(Cs + row * 68 + colg * 4);
      *(float4*)(C + (size_t)(m0 + row) * ldc + n0 + hf * 64 + colg * 4) = v;
    }
  }
}

// ---------------- recurrence: 32 independent 8-block clusters ----------------
// block = b*8 + j. Worker j owns rows {q: j*64..}, {gh_r/z/n: g*512+j*64..} and
// h-dims [j*64,(j+1)*64). Payload protocol (verified r5/r6): relaxed agent-scope
// write-through stores + vmcnt(0) drain + per-step rotating buffers (first-touch
// cold reads) + monotone flags. No global barrier, no fences.

__global__ __launch_bounds__(256) void k_recur(
    const float* __restrict__ Wq, const float* __restrict__ W_hh,
    const float* __restrict__ bq,
    const float* __restrict__ kproj,
    const float* __restrict__ Wv, const float* __restrict__ bv,
    const float* __restrict__ encprojT, const float* __restrict__ giemb,
    const float* __restrict__ b_hh,
    float* h_st, float* partial_st, int* flags,
    float* __restrict__ attn_out, __hip_bfloat16* __restrict__ Hall,
    float* __restrict__ hfin) {
  const int tid = threadIdx.x;
  const int b = blockIdx.x >> 3, j = blockIdx.x & 7;
  int* h_flags  = flags;                // [b*16 + j]
  int* st_flags = flags + 512;          // [b*16 + j]

  const int r8 = tid >> 3, kc = tid & 7;   // GEMV: 32 rows x 8 k-chunks of 64
  __shared__ float q_s[64];
  __shared__ float gh_s[192];
  __shared__ float w_s[64];
  __shared__ float gic_s[192];

  float4 hreg[16];                      // this thread's 64-float h chunk

  for (int t = 0; t < T_; ++t) {
    // ---- wait h_st[t] ready (cluster-local, 8 flags on one line) ----
    if (tid < 8) {
      while (__hip_atomic_load(&h_flags[b * 16 + tid], __ATOMIC_RELAXED,
                               __HIP_MEMORY_SCOPE_AGENT) < t)
        __builtin_amdgcn_s_sleep(2);
    }
    __syncthreads();
    asm volatile("" ::: "memory");

    const float* h_t = h_st + (size_t)t * (B_ * H_) + b * H_;
    const float4* hp4 = (const float4*)h_t;
#pragma unroll
    for (int i = 0; i < 16; ++i) hreg[i] = hp4[kc * 16 + i];

    // ---- q slice: rows j*64..j*64+64 of Wq ----
#pragma unroll
    for (int it = 0; it < 2; ++it) {
      const int row = j * 64 + it * 32 + r8;
      const float4* w4 = (const float4*)(Wq + (size_t)row * H_);
      float p = 0.f;
#pragma unroll
      for (int i = 0; i < 16; ++i) {
        const float4 w = w4[kc * 16 + i];
        p += w.x * hreg[i].x + w.y * hreg[i].y + w.z * hreg[i].z + w.w * hreg[i].w;
      }
      p += __shfl_xor(p, 1); p += __shfl_xor(p, 2); p += __shfl_xor(p, 4);
      if (kc == 0) q_s[it * 32 + r8] = p + bq[row];
    }
    __syncthreads();

    // ---- partial scores over this block's 64 h-dims (tanh is elementwise) ----
    {
      const int s = tid >> 2, q4 = tid & 3;
      const float4* kp = (const float4*)(kproj + ((size_t)(b * S_ + s)) * H_ + j * 64 + q4 * 16);
      const float4* qp = (const float4*)(q_s + q4 * 16);
      const float4* wv = (const float4*)(Wv + j * 64 + q4 * 16);
      float sc = 0.f;
#pragma unroll
      for (int i = 0; i < 4; ++i) {
        const float4 k4 = kp[i], qq = qp[i], vv = wv[i];
        sc += vv.x * fast_tanh(qq.x + k4.x) + vv.y * fast_tanh(qq.y + k4.y)
            + vv.z * fast_tanh(qq.z + k4.z) + vv.w * fast_tanh(qq.w + k4.w);
      }
      sc += __shfl_xor(sc, 1); sc += __shfl_xor(sc, 2);
      if (q4 == 0)
        __hip_atomic_store(&partial_st[(((size_t)t * B_ + b) * 8 + j) * 64 + s], sc,
                           __ATOMIC_RELAXED, __HIP_MEMORY_SCOPE_AGENT);
    }
    asm volatile("s_waitcnt vmcnt(0)" ::: "memory");
    __syncthreads();
    if (tid == 0)
      __hip_atomic_store(&st_flags[b * 16 + j], t + 1, __ATOMIC_RELAXED,
                         __HIP_MEMORY_SCOPE_AGENT);

    // ---- gh slices (overlaps the partial-exchange latency) ----
#pragma unroll
    for (int g = 0; g < 3; ++g)
#pragma unroll
      for (int it = 0; it < 2; ++it) {
        const int row = g * H_ + j * 64 + it * 32 + r8;
        const float4* w4 = (const float4*)(W_hh + (size_t)row * H_);
        float p = 0.f;
#pragma unroll
        for (int i = 0; i < 16; ++i) {
          const float4 w = w4[kc * 16 + i];
          p += w.x * hreg[i].x + w.y * hreg[i].y + w.z * hreg[i].z + w.w * hreg[i].w;
        }
        p += __shfl_xor(p, 1); p += __shfl_xor(p, 2); p += __shfl_xor(p, 4);
        if (kc == 0) gh_s[g * 64 + it * 32 + r8] = p;
      }

    // ---- wait all 8 partials ----
    if (tid < 8) {
      while (__hip_atomic_load(&st_flags[b * 16 + tid], __ATOMIC_RELAXED,
                               __HIP_MEMORY_SCOPE_AGENT) < t + 1)
        __builtin_amdgcn_s_sleep(2);
    }
    __syncthreads();
    asm volatile("" ::: "memory");

    // ---- gather + softmax (redundant per block; bitwise identical) ----
    if (tid < 64) {
      const float* pb = partial_st + ((size_t)t * B_ + b) * 512;
      float sc = bv[0];
#pragma unroll
      for (int jj = 0; jj < 8; ++jj) sc += pb[jj * 64 + tid];
      float m = sc;
#pragma unroll
      for (int d = 32; d > 0; d >>= 1) m = fmaxf(m, __shfl_xor(m, d));
      const float e = __expf(sc - m);
      float sum = e;
#pragma unroll
      for (int d = 32; d > 0; d >>= 1) sum += __shfl_xor(sum, d);
      const float w = e / sum;
      w_s[tid] = w;
      if (j == (b & 7)) attn_out[((size_t)b * T_ + t) * S_ + tid] = w;  // one writer
    }
    __syncthreads();

    // ---- gic slices: gic[row] = sum_s w[s] * encprojT[row][b*64+s] ----
    if (tid < 192) {
      const int g = tid >> 6, dd = tid & 63;
      const int grow = g * H_ + j * 64 + dd;
      const float4* ep = (const float4*)(encprojT + (size_t)grow * 2048 + b * 64);
      const float4* wp = (const float4*)w_s;
      float a = 0.f;
#pragma unroll
      for (int i = 0; i < 16; ++i) {
        const float4 e4 = ep[i], w4 = wp[i];
        a += e4.x * w4.x + e4.y * w4.y + e4.z * w4.z + e4.w * w4.w;
      }
      gic_s[tid] = a;
    }
    __syncthreads();

    // ---- gates for h-dims [j*64,(j+1)*64) ----
    if (tid < 64) {
      const int hh = j * 64 + tid;
      const size_t grow = ((size_t)t * B_ + b) * 1536;
      const float ir  = giemb[grow + hh]        + gic_s[tid];
      const float iz  = giemb[grow + 512 + hh]  + gic_s[64 + tid];
      const float in_ = giemb[grow + 1024 + hh] + gic_s[128 + tid];
      const float hr  = gh_s[tid]        + b_hh[hh];
      const float hz  = gh_s[64 + tid]   + b_hh[512 + hh];
      const float hn  = gh_s[128 + tid]  + b_hh[1024 + hh];
      const float rg = fast_sigmoid(ir + hr);
      const float zg = fast_sigmoid(iz + hz);
      const float ng = fast_tanh(in_ + rg * hn);
      const float ho = h_t[hh];
      const float hv = (1.f - zg) * ng + zg * ho;
      __hip_atomic_store(&h_st[(size_t)(t + 1) * (B_ * H_) + b * H_ + hh], hv,
                         __ATOMIC_RELAXED, __HIP_MEMORY_SCOPE_AGENT);
      Hall[((size_t)b * T_ + t) * H_ + hh] = __float2bfloat16(hv);
      if (t == T_ - 1) hfin[b * H_ + hh] = hv;
    }
    asm volatile("s_waitcnt vmcnt(0)" ::: "memory");
    __syncthreads();
    if (tid == 0)
      __hip_atomic_store(&h_flags[b * 16 + j], t + 1, __ATOMIC_RELAXED,
                         __HIP_MEMORY_SCOPE_AGENT);
  }
}

// ---------------- logits GEMM (XCD-chunked n-tiles): out[m,:] = Hall[m,:] @ Wo^T + bo ----------------

__global__ __launch_bounds__(256) void k_logits(
    const __hip_bfloat16* __restrict__ Hall, const float* __restrict__ Wo,
    const float* __restrict__ bo, float* __restrict__ out0) {
  __shared__ float pool[128 * 68];
  __hip_bfloat16* Asub = (__hip_bfloat16*)pool;
  __hip_bfloat16* Bsub = (__hip_bfloat16*)(pool + 2048);
  const int tid = threadIdx.x;
  const int lane = tid & 63, wave = tid >> 6;
  const int wr = wave >> 1, wc = wave & 1;
  // bijective remap: each XCD gets a contiguous run of n-tiles (Wo L2 reuse)
  const int flat = blockIdx.x;                  // 0..3999
  const int nf = (flat & 7) * 500 + (flat >> 3);
  const int m0 = (nf & 15) * 128, n0 = (nf >> 4) * 128;
  f32x4 acc[4][4];
#pragma unroll
  for (int i = 0; i < 4; ++i)
#pragma unroll
    for (int jj = 0; jj < 4; ++jj) acc[i][jj] = (f32x4){0.f, 0.f, 0.f, 0.f};

  for (int k0 = 0; k0 < 512; k0 += 32) {
    uint4 a_v[2];
#pragma unroll
    for (int rr = 0; rr < 2; ++rr) {
      const int seg = tid + rr * 256;
      const int row = seg >> 2, ks8 = (seg & 3) * 8;
      a_v[rr] = *(const uint4*)(Hall + (size_t)(m0 + row) * 512 + k0 + ks8);
    }
    float4 b_v[4];
#pragma unroll
    for (int rr = 0; rr < 4; ++rr) {
      const int idx = tid + rr * 256;
      const int n = idx >> 3, kg = (idx & 7) * 4;
      b_v[rr] = *(const float4*)(Wo + (size_t)(n0 + n) * 512 + k0 + kg);
    }
    __syncthreads();
#pragma unroll
    for (int rr = 0; rr < 2; ++rr) {
      const int seg = tid + rr * 256;
      *(uint4*)(Asub + seg * 8) = a_v[rr];
    }
#pragma unroll
    for (int rr = 0; rr < 4; ++rr) {
      const int idx = tid + rr * 256;
      const int n = idx >> 3, kg = (idx & 7) * 4;
      union { __hip_bfloat16 h[4]; uint2 u; } cv;
      cv.h[0] = __float2bfloat16(b_v[rr].x);
      cv.h[1] = __float2bfloat16(b_v[rr].y);
      cv.h[2] = __float2bfloat16(b_v[rr].z);
      cv.h[3] = __float2bfloat16(b_v[rr].w);
      *(uint2*)(Bsub + n * 32 + kg) = cv.u;
    }
    __syncthreads();
    bf16x8 af[4], bfr[4];
#pragma unroll
    for (int mi = 0; mi < 4; ++mi)
      af[mi] = *(const bf16x8*)(Asub + (wr * 64 + mi * 16 + (lane & 15)) * 32 + (lane >> 4) * 8);
#pragma unroll
    for (int ni = 0; ni < 4; ++ni)
      bfr[ni] = *(const bf16x8*)(Bsub + (wc * 64 + ni * 16 + (lane & 15)) * 32 + (lane >> 4) * 8);
#pragma unroll
    for (int mi = 0; mi < 4; ++mi)
#pragma unroll
      for (int ni = 0; ni < 4; ++ni)
        acc[mi][ni] = __builtin_amdgcn_mfma_f32_16x16x32_bf16(af[mi], bfr[ni], acc[mi][ni], 0, 0, 0);
  }

  float* Cs = pool;
  const int r4 = (lane >> 4) * 4, cc = lane & 15;
#pragma unroll
  for (int hf = 0; hf < 2; ++hf) {
    __syncthreads();
    if (wc == hf) {
#pragma unroll
      for (int ni = 0; ni < 4; ++ni) {
        const float bias = bo[n0 + hf * 64 + ni * 16 + cc];
#pragma unroll
        for (int mi = 0; mi < 4; ++mi)
#pragma unroll
          for (int i = 0; i < 4; ++i)
            Cs[(wr * 64 + mi * 16 + r4 + i) * 68 + ni * 16 + cc] = acc[mi][ni][i] + bias;
      }
    }
    __syncthreads();
    const int rowp = tid >> 4, colg = tid & 15;
#pragma unroll
    for (int pass = 0; pass < 8; ++pass) {
      const int row = pass * 16 + rowp;
      const float4 v = *(const float4*)(Cs + row * 68 + colg * 4);
      *(float4*)(out0 + (size_t)(m0 + row) * V_ + n0 + hf * 64 + colg * 4) = v;
    }
  }
}

// ---------------- in-place log_softmax over V, one row per block ----------------

__global__ __launch_bounds__(256) void k_lsm(float* __restrict__ out0) {
  __shared__ float rm[256];
  __shared__ float rs[256];
  const int row = blockIdx.x, tid = threadIdx.x;
  float4* p = (float4*)(out0 + (size_t)row * V_);
  float m = -INFINITY, s = 0.f;
  for (int i = tid; i < V_ / 4; i += 256) {
    const float4 v = p[i];
    const float mx = fmaxf(fmaxf(v.x, v.y), fmaxf(v.z, v.w));
    if (mx > m) { s *= __expf(m - mx); m = mx; }
    s += __expf(v.x - m) + __expf(v.y - m) + __expf(v.z - m) + __expf(v.w - m);
  }
  rm[tid] = m; rs[tid] = s;
  __syncthreads();
  for (int off = 128; off > 0; off >>= 1) {
    if (tid < off) {
      const float m2 = rm[tid + off], s2 = rs[tid + off];
      const float M = fmaxf(rm[tid], m2);
      rs[tid] = rs[tid] * __expf(rm[tid] - M) + s2 * __expf(m2 - M);
      rm[tid] = M;
    }
    __syncthreads();
  }
  const float lse = rm[0] + __logf(rs[0]);
  for (int i = tid; i < V_ / 4; i += 256) {
    float4 v = p[i];
    v.x -= lse; v.y -= lse; v.z -= lse; v.w -= lse;
    p[i] = v;
  }
}

// ---------------- host ----------------

extern "C" void kernel_launch(void* const* d_in, const int* in_sizes, int n_in,
                              void* d_out, int out_size, void* d_ws, size_t ws_size,
                              hipStream_t stream) {
  (void)in_sizes; (void)n_in; (void)out_size; (void)ws_size;
  const float* enc  = (const float*)d_in[0];
  const float* ehs  = (const float*)d_in[1];
  const int*   tgt  = (const int*)d_in[2];
  const float* emb  = (const float*)d_in[3];
  const float* Wq   = (const float*)d_in[4];
  const float* bq   = (const float*)d_in[5];
  const float* Wk   = (const float*)d_in[6];
  const float* bk   = (const float*)d_in[7];
  const float* Wv   = (const float*)d_in[8];
  const float* bv   = (const float*)d_in[9];
  const float* W_ih = (const float*)d_in[10];
  const float* W_hh = (const float*)d_in[11];
  const float* b_ih = (const float*)d_in[12];
  const float* b_hh = (const float*)d_in[13];
  const float* Wo   = (const float*)d_in[14];
  const float* bo   = (const float*)d_in[15];

  float* out0 = (float*)d_out;                          // log_probs [2048, V]
  float* out1 = out0 + (size_t)B_ * T_ * V_;            // h_final [B*H]
  float* out2 = out1 + (size_t)B_ * H_;                 // attentions [B*T, S]

  // out0 doubles as scratch; k_logits overwrites all of it afterwards.
  float* kproj    = out0;                 // [0, 1,048,576)
  float* giemb    = out0 + 1048576;       // [.., 4,194,304)
  float* encprojT = out0 + 4194304;       // [1536][2048] -> [.., 7,340,032)
  float* h_st     = out0 + 7340032;       // 65 x 16384 -> [.., 8,404,992)
  float* partial  = out0 + 8404992;       // 64x32x8x64 -> [.., 9,453,568)
  __hip_bfloat16* enc_bf  = (__hip_bfloat16*)(out0 + 9453568);   // 1M bf16
  __hip_bfloat16* emb_bf  = (__hip_bfloat16*)(out0 + 9977856);   // 1M bf16
  __hip_bfloat16* wihc_bf = (__hip_bfloat16*)(out0 + 10502144);  // 0.75M bf16

  __hip_bfloat16* Hall = (__hip_bfloat16*)d_ws;                   // 2 MB
  int* flags = (int*)((char*)d_ws + (size_t)2 * 1024 * 1024);     // 1024 ints

  k_emb_gather<<<2048, 256, 0, stream>>>(tgt, emb, emb_bf);
  k_cvt_dense<<<1024, 256, 0, stream>>>(enc, enc_bf, 262144);
  k_cvt_wihc<<<1536, 128, 0, stream>>>(W_ih, wihc_bf);
  k_init<<<64, 256, 0, stream>>>(ehs, h_st, flags);

  // kproj[2048,512] = enc @ Wk^T + bk
  k_gemm_bf16<<<dim3(4, 16), 256, 0, stream>>>(enc_bf, 512, Wk, 512, bk, kproj, 512, 512);
  // giemb[2048,1536] = emb_all @ W_ih[:, :512]^T + b_ih
  k_gemm_bf16<<<dim3(12, 16), 256, 0, stream>>>(emb_bf, 512, W_ih, 1024, b_ih, giemb, 1536, 512);
  // encprojT[1536,2048] = W_ihc @ enc^T  (row = gic dim, col = b*64+s)
  k_gemm_bf16<<<dim3(16, 12), 256, 0, stream>>>(wihc_bf, 512, enc, 512, nullptr, encprojT, 2048, 512);

  k_recur<<<256, 256, 0, stream>>>(Wq, W_hh, bq, kproj, Wv, bv, encprojT, giemb,
                                   b_hh, h_st, partial, flags, out2, Hall, out1);

  k_logits<<<4000, 256, 0, stream>>>(Hall, Wo, bo, out0);
  k_lsm<<<(B_ * T_), 256, 0, stream>>>(out0);
}